// Round 5
// baseline (317.731 us; speedup 1.0000x reference)
//
#include <hip/hip_runtime.h>
#include <hip/hip_bf16.h>

#define GATE 512
#define MROWS 256
#define NTOT 120581

typedef __attribute__((ext_vector_type(8))) short short8;   // 8 bf16
typedef __attribute__((ext_vector_type(4))) float  f32x4;

struct GemmParams {
    const float* W[10];
    const float* p[10];
    const float* bias[10];
};

__device__ __forceinline__ short bf16bits(float x) {
    __hip_bfloat16 h = __float2bfloat16(x);   // RTNE
    return *reinterpret_cast<short*>(&h);
}

__global__ void emb_to_bf16(const float* __restrict__ emb,
                            unsigned short* __restrict__ o) {
    int i = (blockIdx.x * blockDim.x + threadIdx.x) * 8;
    f32x4 a = *(const f32x4*)(emb + i);
    f32x4 b = *(const f32x4*)(emb + i + 4);
    short8 r;
#pragma unroll
    for (int j = 0; j < 4; ++j) { r[j] = bf16bits(a[j]); r[4 + j] = bf16bits(b[j]); }
    *(short8*)(o + i) = r;
}

// Block: 256 rows x 64 cols; wave w owns cols [w*16,+16) x ALL 256 rows.
//  - W (B operand) is touched by exactly ONE block -> HBM-minimal fetch.
//  - A (emb bf16, 256 KB) is L2-resident: fragments loaded straight from
//    global, no LDS, NO barriers anywhere -> all waits are compiler-counted
//    vmcnt (round-4-style free-running stream, round-2-style traffic).
//  - B register-prefetched 2 K-steps deep.
__global__ __launch_bounds__(256) void gate_gemm(GemmParams P,
                                                 const unsigned short* __restrict__ embw,
                                                 float* __restrict__ out)
{
    constexpr int kStarts[11] = {0, 1728, 1792, 38656, 38720, 75584,
                                 75648, 112512, 112576, 120576, 120581};

    const int t    = threadIdx.x;
    const int lane = t & 63;
    const int wave = t >> 6;
    const int lr   = lane & 15;   // frag col (B/C) / frag row (A)
    const int lg   = lane >> 4;   // k-group / C row-group

    // This lane's single output column
    const int  n     = blockIdx.x * 64 + wave * 16 + lr;
    const bool valid = n < NTOT;
    const int  nc    = valid ? n : NTOT - 1;
    int tt = 0;
#pragma unroll
    for (int i = 1; i < 10; ++i) tt += (nc >= kStarts[i]);
    const int rr = nc - kStarts[tt];
    const float* wrow = P.W[tt] + (size_t)rr * GATE + lg * 8;
    const float pv = P.p[tt][rr];
    const float bv = P.bias[tt][rr];

    // A fragment base: row = mf*16 + lr, k = ks*32 + lg*8
    const unsigned short* arow = embw + lr * GATE + lg * 8;

    f32x4 acc[16];
#pragma unroll
    for (int i = 0; i < 16; ++i) acc[i] = (f32x4){0.f, 0.f, 0.f, 0.f};

    f32x4 Bbuf[3][2];   // rotating, depth-2 prefetch (indices static after unroll)
    auto loadB = [&](f32x4 (&B)[2], int ks) {
        B[0] = *(const f32x4*)(wrow + ks * 32);
        B[1] = *(const f32x4*)(wrow + ks * 32 + 4);
    };

    loadB(Bbuf[0], 0);
    loadB(Bbuf[1], 1);

#pragma unroll
    for (int ks = 0; ks < 16; ++ks) {
        if (ks + 2 < 16) loadB(Bbuf[(ks + 2) % 3], ks + 2);   // HBM, 2 steps ahead

        short8 bfrag;
#pragma unroll
        for (int j = 0; j < 4; ++j) {
            bfrag[j]     = bf16bits(Bbuf[ks % 3][0][j]);
            bfrag[4 + j] = bf16bits(Bbuf[ks % 3][1][j]);
        }

        // First half: issue 8 A-frag loads (L2-hot), then 8 MFMA
        short8 af[8];
#pragma unroll
        for (int mf = 0; mf < 8; ++mf)
            af[mf] = *(const short8*)(arow + mf * 16 * GATE + ks * 32);
#pragma unroll
        for (int mf = 0; mf < 8; ++mf)
            acc[mf] = __builtin_amdgcn_mfma_f32_16x16x32_bf16(af[mf], bfrag, acc[mf], 0, 0, 0);

        // Second half
#pragma unroll
        for (int mf = 0; mf < 8; ++mf)
            af[mf] = *(const short8*)(arow + (mf + 8) * 16 * GATE + ks * 32);
#pragma unroll
        for (int mf = 0; mf < 8; ++mf)
            acc[mf + 8] = __builtin_amdgcn_mfma_f32_16x16x32_bf16(af[mf], bfrag, acc[mf + 8], 0, 0, 0);
    }

    // Epilogue: sigmoid(x + b) * p. C/D map: col = lane&15, row = (lane>>4)*4 + reg.
    // (This exact store geometry measured 1.08x write amplification in round 2.)
    if (valid) {
        float* ocol = out + n;
#pragma unroll
        for (int mf = 0; mf < 16; ++mf) {
            const int m0 = mf * 16 + lg * 4;
#pragma unroll
            for (int q = 0; q < 4; ++q) {
                float x   = acc[mf][q] + bv;
                float e   = __expf(-x);
                float eta = __builtin_amdgcn_rcpf(1.0f + e);
                ocol[(size_t)(m0 + q) * NTOT] = eta * pv;
            }
        }
    }
}

extern "C" void kernel_launch(void* const* d_in, const int* in_sizes, int n_in,
                              void* d_out, int out_size, void* d_ws, size_t ws_size,
                              hipStream_t stream) {
    const float* emb = (const float*)d_in[0];
    GemmParams P;
    for (int i = 0; i < 10; ++i) {
        P.p[i]    = (const float*)d_in[1 + 3 * i];
        P.W[i]    = (const float*)d_in[2 + 3 * i];
        P.bias[i] = (const float*)d_in[3 + 3 * i];
    }

    unsigned short* embw = (unsigned short*)d_ws;   // 256 KB, L2-resident thereafter
    emb_to_bf16<<<(MROWS * GATE) / (256 * 8), 256, 0, stream>>>(emb, embw);

    int nblocks = (NTOT + 63) / 64;   // 1885
    gate_gemm<<<nblocks, 256, 0, stream>>>(P, embw, (float*)d_out);
}

// Round 6
// 316.385 us; speedup vs baseline: 1.0043x; 1.0043x over previous
//
#include <hip/hip_runtime.h>
#include <hip/hip_bf16.h>

#define GATE 512
#define MROWS 256
#define NTOT 120581

typedef __attribute__((ext_vector_type(8))) short short8;   // 8 bf16
typedef __attribute__((ext_vector_type(4))) float  f32x4;

struct GemmParams {
    const float* W[10];
    const float* p[10];
    const float* bias[10];
};

__device__ __forceinline__ short bf16bits(float x) {
    __hip_bfloat16 h = __float2bfloat16(x);   // RTNE
    return *reinterpret_cast<short*>(&h);
}

__global__ void emb_to_bf16(const float* __restrict__ emb,
                            unsigned short* __restrict__ o) {
    int i = (blockIdx.x * blockDim.x + threadIdx.x) * 8;
    f32x4 a = *(const f32x4*)(emb + i);
    f32x4 b = *(const f32x4*)(emb + i + 4);
    short8 r;
#pragma unroll
    for (int j = 0; j < 4; ++j) { r[j] = bf16bits(a[j]); r[4 + j] = bf16bits(b[j]); }
    *(short8*)(o + i) = r;
}

// Block: 256 rows x 64 cols; wave w owns cols [w*16,+16) x ALL 256 rows.
//  - W (B operand) is touched by exactly ONE block -> HBM-minimal fetch.
//  - A (emb bf16, 256 KB) is L2-resident: fragments loaded straight from
//    global, no LDS, NO barriers anywhere -> all waits are compiler-counted
//    vmcnt (round-4-style free-running stream, round-2-style traffic).
//  - B register-prefetched 2 K-steps deep.
__global__ __launch_bounds__(256) void gate_gemm(GemmParams P,
                                                 const unsigned short* __restrict__ embw,
                                                 float* __restrict__ out)
{
    constexpr int kStarts[11] = {0, 1728, 1792, 38656, 38720, 75584,
                                 75648, 112512, 112576, 120576, 120581};

    const int t    = threadIdx.x;
    const int lane = t & 63;
    const int wave = t >> 6;
    const int lr   = lane & 15;   // frag col (B/C) / frag row (A)
    const int lg   = lane >> 4;   // k-group / C row-group

    // This lane's single output column
    const int  n     = blockIdx.x * 64 + wave * 16 + lr;
    const bool valid = n < NTOT;
    const int  nc    = valid ? n : NTOT - 1;
    int tt = 0;
#pragma unroll
    for (int i = 1; i < 10; ++i) tt += (nc >= kStarts[i]);
    const int rr = nc - kStarts[tt];
    const float* wrow = P.W[tt] + (size_t)rr * GATE + lg * 8;
    const float pv = P.p[tt][rr];
    const float bv = P.bias[tt][rr];

    // A fragment base: row = mf*16 + lr, k = ks*32 + lg*8
    const unsigned short* arow = embw + lr * GATE + lg * 8;

    f32x4 acc[16];
#pragma unroll
    for (int i = 0; i < 16; ++i) acc[i] = (f32x4){0.f, 0.f, 0.f, 0.f};

    f32x4 Bbuf[3][2];   // rotating, depth-2 prefetch (indices static after unroll)
    auto loadB = [&](f32x4 (&B)[2], int ks) {
        B[0] = *(const f32x4*)(wrow + ks * 32);
        B[1] = *(const f32x4*)(wrow + ks * 32 + 4);
    };

    loadB(Bbuf[0], 0);
    loadB(Bbuf[1], 1);

#pragma unroll
    for (int ks = 0; ks < 16; ++ks) {
        if (ks + 2 < 16) loadB(Bbuf[(ks + 2) % 3], ks + 2);   // HBM, 2 steps ahead

        short8 bfrag;
#pragma unroll
        for (int j = 0; j < 4; ++j) {
            bfrag[j]     = bf16bits(Bbuf[ks % 3][0][j]);
            bfrag[4 + j] = bf16bits(Bbuf[ks % 3][1][j]);
        }

        // First half: issue 8 A-frag loads (L2-hot), then 8 MFMA
        short8 af[8];
#pragma unroll
        for (int mf = 0; mf < 8; ++mf)
            af[mf] = *(const short8*)(arow + mf * 16 * GATE + ks * 32);
#pragma unroll
        for (int mf = 0; mf < 8; ++mf)
            acc[mf] = __builtin_amdgcn_mfma_f32_16x16x32_bf16(af[mf], bfrag, acc[mf], 0, 0, 0);

        // Second half
#pragma unroll
        for (int mf = 0; mf < 8; ++mf)
            af[mf] = *(const short8*)(arow + (mf + 8) * 16 * GATE + ks * 32);
#pragma unroll
        for (int mf = 0; mf < 8; ++mf)
            acc[mf + 8] = __builtin_amdgcn_mfma_f32_16x16x32_bf16(af[mf], bfrag, acc[mf + 8], 0, 0, 0);
    }

    // Epilogue: sigmoid(x + b) * p. C/D map: col = lane&15, row = (lane>>4)*4 + reg.
    // (This exact store geometry measured 1.08x write amplification in round 2.)
    if (valid) {
        float* ocol = out + n;
#pragma unroll
        for (int mf = 0; mf < 16; ++mf) {
            const int m0 = mf * 16 + lg * 4;
#pragma unroll
            for (int q = 0; q < 4; ++q) {
                float x   = acc[mf][q] + bv;
                float e   = __expf(-x);
                float eta = __builtin_amdgcn_rcpf(1.0f + e);
                ocol[(size_t)(m0 + q) * NTOT] = eta * pv;
            }
        }
    }
}

extern "C" void kernel_launch(void* const* d_in, const int* in_sizes, int n_in,
                              void* d_out, int out_size, void* d_ws, size_t ws_size,
                              hipStream_t stream) {
    const float* emb = (const float*)d_in[0];
    GemmParams P;
    for (int i = 0; i < 10; ++i) {
        P.p[i]    = (const float*)d_in[1 + 3 * i];
        P.W[i]    = (const float*)d_in[2 + 3 * i];
        P.bias[i] = (const float*)d_in[3 + 3 * i];
    }

    unsigned short* embw = (unsigned short*)d_ws;   // 256 KB, L2-resident thereafter
    emb_to_bf16<<<(MROWS * GATE) / (256 * 8), 256, 0, stream>>>(emb, embw);

    int nblocks = (NTOT + 63) / 64;   // 1885
    gate_gemm<<<nblocks, 256, 0, stream>>>(P, embw, (float*)d_out);
}

// Round 7
// 116.224 us; speedup vs baseline: 2.7338x; 2.7222x over previous
//
#include <hip/hip_runtime.h>
#include <hip/hip_bf16.h>

#define GATE 512
#define MROWS 256
#define NTOT 120581
#define PHK 64            // K per LDS phase (8 phases)

typedef __attribute__((ext_vector_type(8))) short short8;   // 8 bf16
typedef __attribute__((ext_vector_type(4))) float  f32x4;

struct GemmParams {
    const float* W[10];
    const float* p[10];
    const float* bias[10];
};

__device__ __forceinline__ short bf16bits(float x) {
    __hip_bfloat16 h = __float2bfloat16(x);   // RTNE
    return *reinterpret_cast<short*>(&h);
}

__global__ void emb_to_bf16(const float* __restrict__ emb,
                            unsigned short* __restrict__ o) {
    int i = (blockIdx.x * blockDim.x + threadIdx.x) * 8;
    f32x4 a = *(const f32x4*)(emb + i);
    f32x4 b = *(const f32x4*)(emb + i + 4);
    short8 r;
#pragma unroll
    for (int j = 0; j < 4; ++j) { r[j] = bf16bits(a[j]); r[4 + j] = bf16bits(b[j]); }
    *(short8*)(o + i) = r;
}

// Block: 256 rows x 64 cols; wave w owns cols [w*16,+16) x ALL 256 rows
// (W fetched by exactly one block; store amp 1.08 measured).
// A staged in LDS (lgkmcnt domain!) double-buffered at K-phase 64; B streamed
// from HBM one full phase ahead (vmcnt counted, never force-drained mid-phase).
// ONE barrier per phase (7 total).
__global__ __launch_bounds__(256) void gate_gemm(GemmParams P,
                                                 const unsigned short* __restrict__ embw,
                                                 float* __restrict__ out)
{
    constexpr int kStarts[11] = {0, 1728, 1792, 38656, 38720, 75584,
                                 75648, 112512, 112576, 120576, 120581};
    __shared__ unsigned short Atile[2][MROWS * PHK];   // 2 x 32 KB

    const int t    = threadIdx.x;
    const int lane = t & 63;
    const int wave = t >> 6;
    const int lr   = lane & 15;   // frag col (B/C) / frag row (A)
    const int lg   = lane >> 4;   // k-group / C row-group

    // This lane's single output column
    const int  n     = blockIdx.x * 64 + wave * 16 + lr;
    const bool valid = n < NTOT;
    const int  nc    = valid ? n : NTOT - 1;
    int tt = 0;
#pragma unroll
    for (int i = 1; i < 10; ++i) tt += (nc >= kStarts[i]);
    const int rr = nc - kStarts[tt];
    const float* wrow = P.W[tt] + (size_t)rr * GATE + lg * 8;
    const float pv = P.p[tt][rr];
    const float bv = P.bias[tt][rr];

    // ---- A staging: pre-swizzled global source, linear LDS dest (m173 pattern).
    // LDS 16B-unit u holds embw[row=u>>3][p*64 + ((u&7)^(row&7))*8 .. +8].
    const int srow0 = t >> 3;                       // + i*32 per load
    const int sslot = (t & 7) ^ ((t >> 3) & 7);     // (i*32)%8==0 -> const over i
    const unsigned short* asrc0 = embw + (size_t)srow0 * GATE + sslot * 8;

    auto stage = [&](int buf, int p) {
#pragma unroll
        for (int i = 0; i < 8; ++i) {
            const unsigned short* src = asrc0 + (size_t)i * 32 * GATE + p * PHK;
            unsigned short* dst = &Atile[buf][(size_t)(i * 256 + t) * 8];
            __builtin_amdgcn_global_load_lds(
                (const __attribute__((address_space(1))) void*)src,
                (__attribute__((address_space(3))) void*)dst, 16, 0, 0);
        }
    };

    // A read: row = mf*16 + lr, chunk slot = ks*4 + lg, stored at slot^(row&7).
    // Bank-quad = (row*8 + slot') % 32 -> max 2-way alias = free (m136).
    const int axor = lr & 7;

    f32x4 acc[16];
#pragma unroll
    for (int i = 0; i < 16; ++i) acc[i] = (f32x4){0.f, 0.f, 0.f, 0.f};

    f32x4 Bc0[2], Bc1[2];
    auto loadB = [&](f32x4 (&B)[2], int gks) {
        B[0] = *(const f32x4*)(wrow + gks * 32);
        B[1] = *(const f32x4*)(wrow + gks * 32 + 4);
    };

    // Prologue: phase 0 A + first two B sub-steps
    stage(0, 0);
    loadB(Bc0, 0);
    loadB(Bc1, 1);
    __syncthreads();

    int buf = 0;
#pragma unroll
    for (int p = 0; p < 8; ++p) {
        f32x4 Bn0[2], Bn1[2];
        if (p < 7) {
            stage(buf ^ 1, p + 1);          // next A phase (overlaps this phase)
            loadB(Bn0, (p + 1) * 2);        // next phase's B, issued a phase early
            loadB(Bn1, (p + 1) * 2 + 1);
        }

        // sub-step 0 (K = p*64 .. +32)
        short8 bf0;
#pragma unroll
        for (int j = 0; j < 4; ++j) { bf0[j] = bf16bits(Bc0[0][j]); bf0[4 + j] = bf16bits(Bc0[1][j]); }
#pragma unroll
        for (int mf = 0; mf < 16; ++mf) {
            const int idx = (mf * 16 + lr) * 64 + ((lg) ^ axor) * 8;
            short8 af = *(const short8*)(&Atile[buf][idx]);
            acc[mf] = __builtin_amdgcn_mfma_f32_16x16x32_bf16(af, bf0, acc[mf], 0, 0, 0);
        }

        // sub-step 1 (K = p*64+32 .. +32)
        short8 bf1;
#pragma unroll
        for (int j = 0; j < 4; ++j) { bf1[j] = bf16bits(Bc1[0][j]); bf1[4 + j] = bf16bits(Bc1[1][j]); }
#pragma unroll
        for (int mf = 0; mf < 16; ++mf) {
            const int idx = (mf * 16 + lr) * 64 + ((4 + lg) ^ axor) * 8;
            short8 af = *(const short8*)(&Atile[buf][idx]);
            acc[mf] = __builtin_amdgcn_mfma_f32_16x16x32_bf16(af, bf1, acc[mf], 0, 0, 0);
        }

        if (p < 7) {
#pragma unroll
            for (int j = 0; j < 2; ++j) { Bc0[j] = Bn0[j]; Bc1[j] = Bn1[j]; }
            __syncthreads();   // stage+B had a full phase of compute to land
            buf ^= 1;
        }
    }

    // Epilogue: sigmoid(x + b) * p. C/D map: col = lane&15, row = (lane>>4)*4 + reg.
    // (Measured 1.08x write amplification in this geometry.)
    if (valid) {
        float* ocol = out + n;
#pragma unroll
        for (int mf = 0; mf < 16; ++mf) {
            const int m0 = mf * 16 + lg * 4;
#pragma unroll
            for (int q = 0; q < 4; ++q) {
                float x   = acc[mf][q] + bv;
                float e   = __expf(-x);
                float eta = __builtin_amdgcn_rcpf(1.0f + e);
                ocol[(size_t)(m0 + q) * NTOT] = eta * pv;
            }
        }
    }
}

extern "C" void kernel_launch(void* const* d_in, const int* in_sizes, int n_in,
                              void* d_out, int out_size, void* d_ws, size_t ws_size,
                              hipStream_t stream) {
    const float* emb = (const float*)d_in[0];
    GemmParams P;
    for (int i = 0; i < 10; ++i) {
        P.p[i]    = (const float*)d_in[1 + 3 * i];
        P.W[i]    = (const float*)d_in[2 + 3 * i];
        P.bias[i] = (const float*)d_in[3 + 3 * i];
    }

    unsigned short* embw = (unsigned short*)d_ws;   // 256 KB, L2-resident
    emb_to_bf16<<<(MROWS * GATE) / (256 * 8), 256, 0, stream>>>(emb, embw);

    int nblocks = (NTOT + 63) / 64;   // 1885
    gate_gemm<<<nblocks, 256, 0, stream>>>(P, embw, (float*)d_out);
}